// Round 5
// baseline (1529.464 us; speedup 1.0000x reference)
//
#include <hip/hip_runtime.h>

// SchNet on MI355X — round 5: weight-stationary persistent k_wf (w2 in VGPRs,
// w1 in LDS, coalesced dwordx4 stores via LDS repack), u32-vectorized gather.
// Linearized coord update + CSR structure retained from round 4.

#define NN 10000
#define EE 320000
#define HH 128
#define GG 50
#define NF 128
#define NL 6

typedef unsigned short u16;
typedef unsigned int u32;
typedef short bf16x8 __attribute__((ext_vector_type(8)));
typedef float f32x4  __attribute__((ext_vector_type(4)));

__device__ __forceinline__ float us2f(u16 u){
  union { float f; u32 i; } v; v.i = ((u32)u) << 16; return v.f;
}
__device__ __forceinline__ u16 f2us(float x){
  union { float f; u32 i; } v; v.f = x;
  u32 r = v.i + 0x7fffu + ((v.i >> 16) & 1u);   // RNE
  return (u16)(r >> 16);
}
__device__ __forceinline__ float ldin(const void* p, int i, int bf){
  return bf ? us2f(((const u16*)p)[i]) : ((const float*)p)[i];
}
__device__ __forceinline__ float sspf(float x){
  return fmaxf(x, 0.f) + __logf(1.f + __expf(-fabsf(x))) - 0.6931472f;
}

// ---------- dtype detection ----------
__global__ void k_dtype(const u32* __restrict__ zraw, const int* __restrict__ ei_raw,
                        int* __restrict__ flags){
  __shared__ int votes[2];
  if(threadIdx.x < 2) votes[threadIdx.x] = 0;
  __syncthreads();
  int v0 = 0, v1 = 0;
  for(int i = threadIdx.x; i < 4096; i += 256){
    u32 w = zraw[i];
    u32 hb = (w >> 8) & 0x7F;
    if(hb >= 0x38 && hb <= 0x41) v0++;
    if(ei_raw[2*i + 1] == 0) v1++;
  }
  atomicAdd(&votes[0], v0); atomicAdd(&votes[1], v1);
  __syncthreads();
  if(threadIdx.x == 0){
    flags[0] = (votes[0] > 2048) ? 1 : 0;
    flags[1] = (votes[1] > 4000) ? 1 : 0;
  }
}

__global__ void k_norm(const int* __restrict__ ei_raw, const int* __restrict__ flags,
                       int* __restrict__ eiN){
  int j = blockIdx.x*256 + threadIdx.x;           // grid exact: 2*EE
  eiN[j] = flags[1] ? ei_raw[2*j] : ei_raw[j];
}

// ---------- weight staging ----------
__global__ void k_prep_weights(
    const void* __restrict__ mlp1_w, const void* __restrict__ mlp1_b,
    const void* __restrict__ mlp2_w, const void* __restrict__ mlp2_b,
    const void* __restrict__ lin1_w, const void* __restrict__ lin2_w,
    const void* __restrict__ lin2_b, const void* __restrict__ lin_w,
    const void* __restrict__ lin_b,  const void* __restrict__ coord_w,
    const void* __restrict__ coord_b, const int* __restrict__ flags,
    float* __restrict__ b1f, float* __restrict__ b2v,
    float* __restrict__ l1t, float* __restrict__ l2t,
    float* __restrict__ l2bf, float* __restrict__ lwt,
    float* __restrict__ lbf, float* __restrict__ cwf, float* __restrict__ cbf,
    u16* __restrict__ w1b, u16* __restrict__ w2b)
{
  int i = blockIdx.x*256 + threadIdx.x;           // grid exact: NL*NF*NF
  int bf = flags[0];
  if(i < NL*NF){
    b1f[i]  = ldin(mlp1_b, i, bf);
    b2v[i]  = ldin(mlp2_b, i, bf);
    l2bf[i] = ldin(lin2_b, i, bf);
    lbf[i]  = ldin(lin_b,  i, bf);
  }
  if(i < NL*NF*64){                               // W1 bf16, K padded 50->64
    int l = i/(NF*64), rem = i%(NF*64);
    int f = rem/64, k = rem%64;
    w1b[i] = (k < GG) ? f2us(ldin(mlp1_w, (l*NF + f)*GG + k, bf)) : (u16)0;
  }
  if(i < NL*NF*NF){
    w2b[i] = f2us(ldin(mlp2_w, i, bf));           // [l][n][k] row-major
    int l = i/(NF*NF), rem = i%(NF*NF);
    int k = rem/NF, f = rem%NF;
    l1t[i] = ldin(lin1_w, l*NF*HH + f*HH + k, bf);
    l2t[i] = ldin(lin2_w, l*HH*NF + f*NF + k, bf);
    lwt[i] = ldin(lin_w,  l*HH*HH + f*HH + k, bf);
  }
  if(i < NL*(GG+2*HH)) cwf[i] = ldin(coord_w, i, bf);
  if(i < NL) cbf[i] = ldin(coord_b, i, bf);
}

__global__ void k_init(const void* __restrict__ z, const void* __restrict__ pos_in,
                       const int* __restrict__ flags,
                       float* __restrict__ h, float* __restrict__ pos){
  int i = blockIdx.x*256 + threadIdx.x;           // grid exact: NN*HH
  int bf = flags[0];
  h[i] = ldin(z, i, bf);
  if(i < NN*3) pos[i] = ldin(pos_in, i, bf);
}

// ---------- edge prep ----------
__global__ void k_edge_prep(const int* __restrict__ eiN, const float* __restrict__ pos,
                            float* __restrict__ wE, float* __restrict__ cE,
                            int* __restrict__ deg_row, int* __restrict__ col_deg){
  int e = blockIdx.x*256 + threadIdx.x;           // grid exact: EE
  int r = eiN[e], c = eiN[EE+e];
  float dx = pos[r*3+0]-pos[c*3+0];
  float dy = pos[r*3+1]-pos[c*3+1];
  float dz = pos[r*3+2]-pos[c*3+2];
  float w = sqrtf(dx*dx + dy*dy + dz*dz);
  wE[e] = w;
  cE[e] = 0.5f*(cosf(w*0.3141592653589793f) + 1.f);
  atomicAdd(&deg_row[r], 1);
  atomicAdd(&col_deg[c], 1);
}

// generic single-block exclusive scan (N=10000)
__global__ void k_scan(const int* __restrict__ deg, int* __restrict__ start,
                       int* __restrict__ nxt){
  __shared__ int part[1024];
  int tid = threadIdx.x;
  const int CH = (NN + 1023)/1024;
  int base = tid*CH;
  int s = 0;
  for(int i=0;i<CH;i++){ int idx=base+i; if(idx<NN) s += deg[idx]; }
  part[tid] = s;
  __syncthreads();
  for(int off=1; off<1024; off<<=1){
    int v = (tid>=off) ? part[tid-off] : 0;
    __syncthreads();
    part[tid] += v;
    __syncthreads();
  }
  int run = (tid==0) ? 0 : part[tid-1];
  for(int i=0;i<CH;i++){
    int idx = base+i;
    if(idx<NN){ start[idx]=run; nxt[idx]=run; run += deg[idx]; }
  }
  if(tid==1023) start[NN] = run;
}

__global__ void k_fillC(const int* __restrict__ eiN, const float* __restrict__ wE,
                        const float* __restrict__ cE, int* __restrict__ col_next,
                        int* __restrict__ row_s, float* __restrict__ wEs,
                        float* __restrict__ cEs){
  int e = blockIdx.x*256 + threadIdx.x;           // grid exact: EE
  int c = eiN[EE+e];
  int p = atomicAdd(&col_next[c], 1);
  row_s[p] = eiN[e];
  wEs[p] = wE[e];
  cEs[p] = cE[e];
}

__global__ void k_fillR(const int* __restrict__ eiN, const float* __restrict__ wE,
                        int* __restrict__ row_next,
                        int* __restrict__ rcol_s, float* __restrict__ rw_s){
  int e = blockIdx.x*256 + threadIdx.x;           // grid exact: EE
  int r = eiN[e];
  int p = atomicAdd(&row_next[r], 1);
  rcol_s[p] = eiN[EE+e];
  rw_s[p] = wE[e];
}

// ---------- per-node dots ----------
__global__ void k_nodedot(const float* __restrict__ h, const float* __restrict__ cwf,
                          int l, float* __restrict__ d_r, float* __restrict__ d_c){
  int lane = threadIdx.x & 63;
  int n = (blockIdx.x*256 + threadIdx.x) >> 6;    // grid exact: NN/4 blocks
  const float* __restrict__ cw = cwf + l*(GG + 2*HH);
  float h0 = h[n*HH + lane], h1 = h[n*HH + 64 + lane];
  float ar = h0*cw[GG + lane]      + h1*cw[GG + 64 + lane];
  float ac = h0*cw[GG + HH + lane] + h1*cw[GG + HH + 64 + lane];
  #pragma unroll
  for(int s=32; s>0; s>>=1){
    ar += __shfl_down(ar, s, 64);
    ac += __shfl_down(ac, s, 64);
  }
  if(lane == 0){ d_r[n] = ar; d_c[n] = ac; }
}

// ---------- coord update: row-CSR gather + mean + pos (ping-pong) ----------
__global__ void k_coordagg(const int* __restrict__ row_start, const int* __restrict__ rcol_s,
                           const float* __restrict__ rw_s, const float* __restrict__ d_r,
                           const float* __restrict__ d_c, const float* __restrict__ cwf,
                           const float* __restrict__ cbf, int l,
                           const float* __restrict__ pA, float* __restrict__ pB){
  int lane = threadIdx.x & 63;
  int n = (blockIdx.x*256 + threadIdx.x) >> 6;    // grid exact: NN/4 blocks
  const float* __restrict__ cwg = cwf + l*(GG + 2*HH);
  float cb = cbf[l] + d_r[n];
  int p0 = row_start[n], p1 = row_start[n+1];
  float px = pA[n*3+0], py = pA[n*3+1], pz = pA[n*3+2];
  float sx=0.f, sy=0.f, sz=0.f;
  for(int p = p0 + lane; p < p1; p += 64){
    int c = rcol_s[p];
    float w = rw_s[p];
    float acc = cb + d_c[c];
    #pragma unroll 10
    for(int g=0; g<GG; g++){
      float d = w - (float)g*(10.f/49.f);
      acc += __expf(-12.005f*d*d) * cwg[g];
    }
    sx += (px - pA[c*3+0])*acc;
    sy += (py - pA[c*3+1])*acc;
    sz += (pz - pA[c*3+2])*acc;
  }
  #pragma unroll
  for(int s=32; s>0; s>>=1){
    sx += __shfl_down(sx, s, 64);
    sy += __shfl_down(sy, s, 64);
    sz += __shfl_down(sz, s, 64);
  }
  if(lane == 0){
    int cnt = p1 - p0;
    float inv = (cnt > 0) ? 1.f/(float)cnt : 0.f;
    pB[n*3+0] = px + sx*inv;
    pB[n*3+1] = py + sy*inv;
    pB[n*3+2] = pz + sz*inv;
  }
}

// ---------- xf = h @ lin1^T (bf16 out) ----------
__global__ void k_xf(const float* __restrict__ h, const float* __restrict__ l1t,
                     int l, u16* __restrict__ xfb){
  int f = threadIdx.x;
  int n0 = blockIdx.x*8;                          // grid exact: NN/8
  const float* __restrict__ wt = l1t + l*HH*NF;
  float acc[8];
  #pragma unroll
  for(int i=0;i<8;i++) acc[i] = 0.f;
  for(int k=0;k<HH;k++){
    float wv = wt[k*NF + f];
    #pragma unroll
    for(int i=0;i<8;i++) acc[i] += h[(n0+i)*HH + k] * wv;
  }
  #pragma unroll
  for(int i=0;i<8;i++) xfb[(n0+i)*NF + f] = f2us(acc[i]);
}

// ---------- edge MLP, weight-stationary persistent MFMA kernel ----------
// grid 512 blocks x 256 thr (4 waves). w2 B-frags in VGPRs (32 x bf16x8),
// w1 in LDS (stride 72 u16 = 144 B, 16B-aligned, 2-way banks). Each wave does
// a 16-edge tile per iteration: gaussians -> regs -> GEMM1 -> ssp -> LDS T ->
// GEMM2 -> scale -> LDS repack -> 4x dwordx4 coalesced stores.
#define WF_GRID 512
__global__ __launch_bounds__(256, 2)
void k_wf(const float* __restrict__ wEs, const float* __restrict__ cEs,
          const u16* __restrict__ w1b, const float* __restrict__ b1f,
          const u16* __restrict__ w2b, const float* __restrict__ b2v,
          int l, u16* __restrict__ Wf){
  __shared__ __align__(16) u16 w1lds[128*72];
  __shared__ __align__(16) u16 T[4*16*136];       // per-wave 16x136 (272 B rows)
  int t = threadIdx.x;
  int lane = t & 63;
  int m16  = lane & 15;
  int quad = lane >> 4;
  int wave = t >> 6;

  // stage w1 layer into LDS (once per block)
  {
    const u16* __restrict__ w1g = w1b + l*NF*64;
    #pragma unroll
    for(int c = 0; c < 4; c++){
      int idx = c*256 + t;                        // 1024 chunks of 8 u16
      int row = idx >> 3, ko = (idx & 7)*8;
      *(uint4*)&w1lds[row*72 + ko] = *(const uint4*)&w1g[row*64 + ko];
    }
  }
  // loop-invariant: w2 B-frags into VGPRs, biases
  bf16x8 w2f[4][8];                               // [kstep][nt]
  {
    const u16* __restrict__ w2 = w2b + l*NF*NF;
    #pragma unroll
    for(int ks=0; ks<4; ks++)
      #pragma unroll
      for(int nt=0; nt<8; nt++)
        w2f[ks][nt] = *(const bf16x8*)&w2[(nt*16 + m16)*128 + ks*32 + quad*8];
  }
  float b1v[8], b2vv[8];
  #pragma unroll
  for(int nt=0; nt<8; nt++){
    b1v[nt]  = b1f[l*NF + nt*16 + m16];
    b2vv[nt] = b2v[l*NF + nt*16 + m16];
  }
  __syncthreads();

  u16* __restrict__ Tw = &T[wave*16*136];
  const int NT = EE/64;                           // 5000 tiles of 64 edges
  for(int tile = blockIdx.x; tile < NT; tile += WF_GRID){
    int p0w = tile*64 + wave*16;                  // this wave's 16 edges
    float w = wEs[p0w + m16];

    // A-frags from gaussians, straight into registers
    bf16x8 aF[2];
    #pragma unroll
    for(int ks=0; ks<2; ks++){
      #pragma unroll
      for(int j=0; j<8; j++){
        int col = ks*32 + quad*8 + j;
        float d = w - (float)col*(10.f/49.f);
        float v = __expf(-12.005f*d*d);
        aF[ks][j] = (short)((col < GG) ? f2us(v) : (u16)0);
      }
    }
    // GEMM1 (K=64): w1 from LDS
    f32x4 acc[8];
    #pragma unroll
    for(int nt=0; nt<8; nt++) acc[nt] = (f32x4){b1v[nt],b1v[nt],b1v[nt],b1v[nt]};
    #pragma unroll
    for(int ks=0; ks<2; ks++){
      #pragma unroll
      for(int nt=0; nt<8; nt++){
        bf16x8 b = *(const bf16x8*)&w1lds[(nt*16 + m16)*72 + ks*32 + quad*8];
        acc[nt] = __builtin_amdgcn_mfma_f32_16x16x32_bf16(aF[ks], b, acc[nt], 0, 0, 0);
      }
    }
    // ssp -> T (wave-private, program-order safe)
    #pragma unroll
    for(int nt=0; nt<8; nt++)
      #pragma unroll
      for(int r=0; r<4; r++)
        Tw[(quad*4 + r)*136 + nt*16 + m16] = f2us(sspf(acc[nt][r]));

    // GEMM2 (K=128): A from T, B from VGPRs
    #pragma unroll
    for(int nt=0; nt<8; nt++) acc[nt] = (f32x4){b2vv[nt],b2vv[nt],b2vv[nt],b2vv[nt]};
    #pragma unroll
    for(int ks=0; ks<4; ks++){
      bf16x8 a = *(const bf16x8*)&Tw[m16*136 + ks*32 + quad*8];
      #pragma unroll
      for(int nt=0; nt<8; nt++)
        acc[nt] = __builtin_amdgcn_mfma_f32_16x16x32_bf16(a, w2f[ks][nt], acc[nt], 0, 0, 0);
    }
    // scale by cutoff, repack via T, coalesced dwordx4 stores
    f32x4 cc = *(const f32x4*)&cEs[p0w + quad*4];
    #pragma unroll
    for(int nt=0; nt<8; nt++)
      #pragma unroll
      for(int r=0; r<4; r++)
        Tw[(quad*4 + r)*136 + nt*16 + m16] = f2us(acc[nt][r]*cc[r]);
    #pragma unroll
    for(int it=0; it<4; it++){
      int row = it*4 + quad;                      // wait: need rows 0..15 over (it,lane>>4)
      uint4 v = *(const uint4*)&Tw[row*136 + m16*8];
      *(uint4*)&Wf[(p0w + row)*NF + m16*8] = v;
    }
  }
}

// ---------- agg[n][f] = sum_p xf[row][f]*Wf[p][f], u32 bf16-pair vectorized ----------
__global__ void k_gather(const int* __restrict__ col_start, const int* __restrict__ row_s,
                         const u32* __restrict__ xfb32, const u32* __restrict__ Wf32,
                         float* __restrict__ agg){
  int n = blockIdx.x*4 + (threadIdx.x >> 6);      // grid exact: NN/4
  int q = threadIdx.x & 63;                       // feature pair index
  int p0 = col_start[n], p1 = col_start[n+1];
  float a0=0.f, a1=0.f, b0=0.f, b1=0.f;
  int p = p0;
  for(; p+2 <= p1; p += 2){
    int r0 = row_s[p], r1 = row_s[p+1];
    u32 x0 = xfb32[r0*64 + q], w0 = Wf32[(size_t)p*64 + q];
    u32 x1 = xfb32[r1*64 + q], w1 = Wf32[(size_t)(p+1)*64 + q];
    a0 += us2f((u16)x0)*us2f((u16)w0);
    b0 += us2f((u16)(x0>>16))*us2f((u16)(w0>>16));
    a1 += us2f((u16)x1)*us2f((u16)w1);
    b1 += us2f((u16)(x1>>16))*us2f((u16)(w1>>16));
  }
  if(p < p1){
    u32 x0 = xfb32[row_s[p]*64 + q], w0 = Wf32[(size_t)p*64 + q];
    a0 += us2f((u16)x0)*us2f((u16)w0);
    b0 += us2f((u16)(x0>>16))*us2f((u16)(w0>>16));
  }
  float2 r; r.x = a0+a1; r.y = b0+b1;
  *(float2*)&agg[n*NF + q*2] = r;
}

// ---------- h += ssp(agg@lin2^T + b) @ lin^T + b ----------
__global__ void k_update(const float* __restrict__ agg, const float* __restrict__ l2t,
                         const float* __restrict__ l2bf, const float* __restrict__ lwt,
                         const float* __restrict__ lbf, int l, float* __restrict__ h){
  __shared__ float sg[HH*12];
  int f = threadIdx.x;
  int n0 = blockIdx.x*8;                          // grid exact: NN/8
  const float* __restrict__ wA = l2t + l*NF*HH;
  float bA = l2bf[l*HH + f];
  float acc[8];
  #pragma unroll
  for(int i=0;i<8;i++) acc[i] = bA;
  for(int k=0;k<NF;k++){
    float wv = wA[k*HH + f];
    #pragma unroll
    for(int i=0;i<8;i++) acc[i] += agg[(n0+i)*NF + k] * wv;
  }
  #pragma unroll
  for(int i=0;i<8;i++) sg[f*12 + i] = sspf(acc[i]);
  __syncthreads();
  const float* __restrict__ wB = lwt + l*HH*HH;
  float bB = lbf[l*HH + f];
  float acc2[8];
  #pragma unroll
  for(int i=0;i<8;i++) acc2[i] = bB;
  for(int k=0;k<HH;k++){
    float wv = wB[k*HH + f];
    #pragma unroll
    for(int i=0;i<8;i++) acc2[i] += sg[k*12 + i] * wv;
  }
  #pragma unroll
  for(int i=0;i<8;i++) h[(n0+i)*HH + f] += acc2[i];
}

__global__ void k_out(const float* __restrict__ pos, const float* __restrict__ h,
                      const int* __restrict__ flags, void* __restrict__ out){
  int i = blockIdx.x*256 + threadIdx.x;           // grid exact: NN*HH
  if(flags[0]){
    u16* o = (u16*)out;
    if(i < NN*3) o[i] = f2us(pos[i]);
    o[NN*3 + i] = f2us(h[i]);
  } else {
    float* o = (float*)out;
    if(i < NN*3) o[i] = pos[i];
    o[NN*3 + i] = h[i];
  }
}

extern "C" void kernel_launch(void* const* d_in, const int* in_sizes, int n_in,
                              void* d_out, int out_size, void* d_ws, size_t ws_size,
                              hipStream_t stream){
  const void* z      = d_in[0];
  const void* pos_in = d_in[1];
  const int*  ei_raw = (const int*)d_in[2];
  const void* mlp1_w = d_in[3];
  const void* mlp1_b = d_in[4];
  const void* mlp2_w = d_in[5];
  const void* mlp2_b = d_in[6];
  const void* lin1_w = d_in[7];
  const void* lin2_w = d_in[8];
  const void* lin2_b = d_in[9];
  const void* lin_w  = d_in[10];
  const void* lin_b  = d_in[11];
  const void* coord_w= d_in[12];
  const void* coord_b= d_in[13];

  float* W = (float*)d_ws;
  float* h    = W; W += NN*HH;
  float* agg  = W; W += NN*NF;
  float* posA = W; W += NN*3;
  float* posB = W; W += NN*3;
  float* d_r  = W; W += NN;
  float* d_c  = W; W += NN;
  float* wE   = W; W += EE;
  float* cE   = W; W += EE;
  float* wEs  = W; W += EE;
  float* cEs  = W; W += EE;
  float* rw_s = W; W += EE;
  float* b1f  = W; W += NL*NF;
  float* b2v  = W; W += NL*NF;
  float* l1t  = W; W += NL*NF*HH;
  float* l2t  = W; W += NL*HH*NF;
  float* l2bf = W; W += NL*HH;
  float* lwt  = W; W += NL*HH*HH;
  float* lbf  = W; W += NL*HH;
  float* cwf  = W; W += NL*(GG+2*HH);
  float* cbf  = W; W += NL;
  W = (float*)(((uintptr_t)W + 63) & ~(uintptr_t)63);
  u16* w1b = (u16*)W; W += (NL*NF*64)/2;
  u16* w2b = (u16*)W; W += (NL*NF*NF)/2;
  u16* Wf  = (u16*)W; W += (EE*NF)/2;             // edge-major [p][f] bf16
  u16* xfb = (u16*)W; W += (NN*NF)/2;             // bf16 xf
  int* deg_row   = (int*)W; W += NN;
  int* col_deg   = (int*)W; W += NN;
  int* col_start = (int*)W; W += NN+1;
  int* col_next  = (int*)W; W += NN;
  int* row_start = (int*)W; W += NN+1;
  int* row_next  = (int*)W; W += NN;
  int* row_s     = (int*)W; W += EE;
  int* rcol_s    = (int*)W; W += EE;
  int* eiN       = (int*)W; W += 2*EE;
  int* flags     = (int*)W; W += 2;

  hipMemsetAsync(deg_row, 0, NN*sizeof(int), stream);
  hipMemsetAsync(col_deg, 0, NN*sizeof(int), stream);

  k_dtype<<<1, 256, 0, stream>>>((const u32*)z, ei_raw, flags);
  k_norm<<<(2*EE)/256, 256, 0, stream>>>(ei_raw, flags, eiN);
  k_prep_weights<<<(NL*NF*NF)/256, 256, 0, stream>>>(
      mlp1_w, mlp1_b, mlp2_w, mlp2_b, lin1_w, lin2_w, lin2_b, lin_w, lin_b,
      coord_w, coord_b, flags,
      b1f, b2v, l1t, l2t, l2bf, lwt, lbf, cwf, cbf, w1b, w2b);
  k_init<<<(NN*HH)/256, 256, 0, stream>>>(z, pos_in, flags, h, posA);
  k_edge_prep<<<EE/256, 256, 0, stream>>>(eiN, posA, wE, cE, deg_row, col_deg);
  k_scan<<<1, 1024, 0, stream>>>(col_deg, col_start, col_next);
  k_scan<<<1, 1024, 0, stream>>>(deg_row, row_start, row_next);
  k_fillC<<<EE/256, 256, 0, stream>>>(eiN, wE, cE, col_next, row_s, wEs, cEs);
  k_fillR<<<EE/256, 256, 0, stream>>>(eiN, wE, row_next, rcol_s, rw_s);

  float* pA = posA;
  float* pB = posB;
  for(int l=0; l<NL; l++){
    k_nodedot<<<NN/4, 256, 0, stream>>>(h, cwf, l, d_r, d_c);
    k_coordagg<<<NN/4, 256, 0, stream>>>(row_start, rcol_s, rw_s, d_r, d_c,
                                         cwf, cbf, l, pA, pB);
    k_xf<<<NN/8, 128, 0, stream>>>(h, l1t, l, xfb);
    k_wf<<<WF_GRID, 256, 0, stream>>>(wEs, cEs, w1b, b1f, w2b, b2v, l, Wf);
    k_gather<<<NN/4, 256, 0, stream>>>(col_start, row_s, (const u32*)xfb,
                                       (const u32*)Wf, agg);
    k_update<<<NN/8, 128, 0, stream>>>(agg, l2t, l2bf, lwt, lbf, l, h);
    float* tmp = pA; pA = pB; pB = tmp;
  }
  k_out<<<(NN*HH)/256, 256, 0, stream>>>(pA, h, flags, (void*)d_out);
}

// Round 6
// 854.767 us; speedup vs baseline: 1.7893x; 1.7893x over previous
//
#include <hip/hip_runtime.h>

// SchNet on MI355X — round 6: edge MLP replaced by per-layer 1-D lookup table
// G_l(w) (2048 pts, linear interp; err ~3e-5 << bf16 noise), fused into the
// aggregation gather. Coord gaussian term also tabulated (tabS). k_wf and the
// 80 MB Wf buffer are gone. CSR structure + linearized coord update retained.

#define NN 10000
#define EE 320000
#define HH 128
#define GG 50
#define NF 128
#define NL 6
#define TROWS 2048

typedef unsigned short u16;
typedef unsigned int u32;

__device__ __forceinline__ float us2f(u16 u){
  union { float f; u32 i; } v; v.i = ((u32)u) << 16; return v.f;
}
__device__ __forceinline__ u16 f2us(float x){
  union { float f; u32 i; } v; v.f = x;
  u32 r = v.i + 0x7fffu + ((v.i >> 16) & 1u);   // RNE
  return (u16)(r >> 16);
}
__device__ __forceinline__ float ldin(const void* p, int i, int bf){
  return bf ? us2f(((const u16*)p)[i]) : ((const float*)p)[i];
}
__device__ __forceinline__ float sspf(float x){
  return fmaxf(x, 0.f) + __logf(1.f + __expf(-fabsf(x))) - 0.6931472f;
}

// ---------- dtype detection ----------
__global__ void k_dtype(const u32* __restrict__ zraw, const int* __restrict__ ei_raw,
                        int* __restrict__ flags){
  __shared__ int votes[2];
  if(threadIdx.x < 2) votes[threadIdx.x] = 0;
  __syncthreads();
  int v0 = 0, v1 = 0;
  for(int i = threadIdx.x; i < 4096; i += 256){
    u32 w = zraw[i];
    u32 hb = (w >> 8) & 0x7F;
    if(hb >= 0x38 && hb <= 0x41) v0++;
    if(ei_raw[2*i + 1] == 0) v1++;
  }
  atomicAdd(&votes[0], v0); atomicAdd(&votes[1], v1);
  __syncthreads();
  if(threadIdx.x == 0){
    flags[0] = (votes[0] > 2048) ? 1 : 0;
    flags[1] = (votes[1] > 4000) ? 1 : 0;
  }
}

__global__ void k_norm(const int* __restrict__ ei_raw, const int* __restrict__ flags,
                       int* __restrict__ eiN){
  int j = blockIdx.x*256 + threadIdx.x;           // grid exact: 2*EE
  eiN[j] = flags[1] ? ei_raw[2*j] : ei_raw[j];
}

// ---------- weight staging (all fp32, transposed where consumer needs [k][f]) ----------
__global__ void k_prep_weights(
    const void* __restrict__ mlp1_w, const void* __restrict__ mlp1_b,
    const void* __restrict__ mlp2_w, const void* __restrict__ mlp2_b,
    const void* __restrict__ lin1_w, const void* __restrict__ lin2_w,
    const void* __restrict__ lin2_b, const void* __restrict__ lin_w,
    const void* __restrict__ lin_b,  const void* __restrict__ coord_w,
    const void* __restrict__ coord_b, const int* __restrict__ flags,
    float* __restrict__ b1f, float* __restrict__ b2v,
    float* __restrict__ w1t, float* __restrict__ w2t,
    float* __restrict__ l1t, float* __restrict__ l2t,
    float* __restrict__ l2bf, float* __restrict__ lwt,
    float* __restrict__ lbf, float* __restrict__ cwf, float* __restrict__ cbf)
{
  int i = blockIdx.x*256 + threadIdx.x;           // grid exact: NL*NF*NF
  int bf = flags[0];
  if(i < NL*NF){
    b1f[i]  = ldin(mlp1_b, i, bf);
    b2v[i]  = ldin(mlp2_b, i, bf);
    l2bf[i] = ldin(lin2_b, i, bf);
    lbf[i]  = ldin(lin_b,  i, bf);
  }
  if(i < NL*GG*NF){                               // w1t[l][g][f] = mlp1_w[l][f][g]
    int l = i/(GG*NF), rem = i%(GG*NF);
    int g = rem/NF, f = rem%NF;
    w1t[i] = ldin(mlp1_w, (l*NF + f)*GG + g, bf);
  }
  if(i < NL*NF*NF){
    int l = i/(NF*NF), rem = i%(NF*NF);
    int k = rem/NF, f = rem%NF;
    w2t[i] = ldin(mlp2_w, l*NF*NF + f*NF + k, bf);
    l1t[i] = ldin(lin1_w, l*NF*HH + f*HH + k, bf);
    l2t[i] = ldin(lin2_w, l*HH*NF + f*NF + k, bf);
    lwt[i] = ldin(lin_w,  l*HH*HH + f*HH + k, bf);
  }
  if(i < NL*(GG+2*HH)) cwf[i] = ldin(coord_w, i, bf);
  if(i < NL) cbf[i] = ldin(coord_b, i, bf);
}

__global__ void k_init(const void* __restrict__ z, const void* __restrict__ pos_in,
                       const int* __restrict__ flags,
                       float* __restrict__ h, float* __restrict__ pos){
  int i = blockIdx.x*256 + threadIdx.x;           // grid exact: NN*HH
  int bf = flags[0];
  h[i] = ldin(z, i, bf);
  if(i < NN*3) pos[i] = ldin(pos_in, i, bf);
}

// ---------- edge prep: distances (INITIAL pos), degrees, w_max ----------
__global__ void k_edge_prep(const int* __restrict__ eiN, const float* __restrict__ pos,
                            float* __restrict__ wE,
                            int* __restrict__ deg_row, int* __restrict__ col_deg,
                            int* __restrict__ wmaxi){
  int e = blockIdx.x*256 + threadIdx.x;           // grid exact: EE
  int r = eiN[e], c = eiN[EE+e];
  float dx = pos[r*3+0]-pos[c*3+0];
  float dy = pos[r*3+1]-pos[c*3+1];
  float dz = pos[r*3+2]-pos[c*3+2];
  float w = sqrtf(dx*dx + dy*dy + dz*dz);
  wE[e] = w;
  atomicMax(wmaxi, __float_as_int(w));            // w>=0: int-bit compare monotone
  atomicAdd(&deg_row[r], 1);
  atomicAdd(&col_deg[c], 1);
}

// generic single-block exclusive scan (N=10000)
__global__ void k_scan(const int* __restrict__ deg, int* __restrict__ start,
                       int* __restrict__ nxt){
  __shared__ int part[1024];
  int tid = threadIdx.x;
  const int CH = (NN + 1023)/1024;
  int base = tid*CH;
  int s = 0;
  for(int i=0;i<CH;i++){ int idx=base+i; if(idx<NN) s += deg[idx]; }
  part[tid] = s;
  __syncthreads();
  for(int off=1; off<1024; off<<=1){
    int v = (tid>=off) ? part[tid-off] : 0;
    __syncthreads();
    part[tid] += v;
    __syncthreads();
  }
  int run = (tid==0) ? 0 : part[tid-1];
  for(int i=0;i<CH;i++){
    int idx = base+i;
    if(idx<NN){ start[idx]=run; nxt[idx]=run; run += deg[idx]; }
  }
  if(tid==1023) start[NN] = run;
}

// col-CSR fill: row id + edge w into col-sorted order
__global__ void k_fillC(const int* __restrict__ eiN, const float* __restrict__ wE,
                        int* __restrict__ col_next,
                        int* __restrict__ row_s, float* __restrict__ wEs){
  int e = blockIdx.x*256 + threadIdx.x;           // grid exact: EE
  int c = eiN[EE+e];
  int p = atomicAdd(&col_next[c], 1);
  row_s[p] = eiN[e];
  wEs[p] = wE[e];
}

// row-CSR fill
__global__ void k_fillR(const int* __restrict__ eiN, const float* __restrict__ wE,
                        int* __restrict__ row_next,
                        int* __restrict__ rcol_s, float* __restrict__ rw_s){
  int e = blockIdx.x*256 + threadIdx.x;           // grid exact: EE
  int r = eiN[e];
  int p = atomicAdd(&row_next[r], 1);
  rcol_s[p] = eiN[EE+e];
  rw_s[p] = wE[e];
}

// ---------- build lookup tables for all layers ----------
// tabG[l][i][f] = C(w_i) * (mlp2(ssp(mlp1(gauss(w_i)))))[f]
// tabS[l][i]    = sum_g gauss_g(w_i) * coord_w[l][g]
// grid (TROWS/8, NL) x 128 threads; 8 w-rows per block.
__global__ void k_table(const float* __restrict__ w1t, const float* __restrict__ b1f,
                        const float* __restrict__ w2t, const float* __restrict__ b2v,
                        const float* __restrict__ cwf, const int* __restrict__ wmaxi,
                        float* __restrict__ tabG, float* __restrict__ tabS){
  __shared__ float attr[8][64];
  __shared__ float tls[128][9];                   // [k][r], stride 9: conflict-free
  int f = threadIdx.x;                            // 128
  int l = blockIdx.y;
  int r0 = blockIdx.x*8;
  float delta = __int_as_float(*wmaxi) / (float)(TROWS-1);
  for(int idx=f; idx<8*64; idx+=128){
    int r = idx>>6, g = idx&63;
    float w = (float)(r0+r)*delta;
    float d = w - (float)g*(10.f/49.f);
    attr[r][g] = (g < GG) ? __expf(-12.005f*d*d) : 0.f;
  }
  __syncthreads();
  const float* __restrict__ w1 = w1t + l*GG*NF;
  float b1 = b1f[l*NF + f];
  float acc[8];
  #pragma unroll
  for(int r=0;r<8;r++) acc[r] = b1;
  for(int g=0; g<GG; g++){
    float wv = w1[g*NF + f];
    #pragma unroll
    for(int r=0;r<8;r++) acc[r] += attr[r][g]*wv;
  }
  #pragma unroll
  for(int r=0;r<8;r++) tls[f][r] = sspf(acc[r]);
  __syncthreads();
  const float* __restrict__ w2 = w2t + l*NF*NF;
  float b2 = b2v[l*NF + f];
  float acc2[8];
  #pragma unroll
  for(int r=0;r<8;r++) acc2[r] = b2;
  for(int k=0;k<NF;k++){
    float wv = w2[k*NF + f];
    #pragma unroll
    for(int r=0;r<8;r++) acc2[r] += tls[k][r]*wv;
  }
  #pragma unroll
  for(int r=0;r<8;r++){
    float w = (float)(r0+r)*delta;
    float C = 0.5f*(cosf(w*0.3141592653589793f) + 1.f);
    tabG[((size_t)l*TROWS + r0 + r)*NF + f] = acc2[r]*C;
  }
  if(f < 8){
    const float* __restrict__ cwg = cwf + l*(GG+2*HH);
    float s = 0.f;
    for(int g=0; g<GG; g++) s += attr[f][g]*cwg[g];
    tabS[l*TROWS + r0 + f] = s;
  }
}

// ---------- per-node dots for linearized coord update ----------
__global__ void k_nodedot(const float* __restrict__ h, const float* __restrict__ cwf,
                          int l, float* __restrict__ d_r, float* __restrict__ d_c){
  int lane = threadIdx.x & 63;
  int n = (blockIdx.x*256 + threadIdx.x) >> 6;    // grid exact: NN/4
  const float* __restrict__ cw = cwf + l*(GG + 2*HH);
  float h0 = h[n*HH + lane], h1 = h[n*HH + 64 + lane];
  float ar = h0*cw[GG + lane]      + h1*cw[GG + 64 + lane];
  float ac = h0*cw[GG + HH + lane] + h1*cw[GG + HH + 64 + lane];
  #pragma unroll
  for(int s=32; s>0; s>>=1){
    ar += __shfl_down(ar, s, 64);
    ac += __shfl_down(ac, s, 64);
  }
  if(lane == 0){ d_r[n] = ar; d_c[n] = ac; }
}

// ---------- coord update: row-CSR gather, gauss term via tabS lerp ----------
__global__ void k_coordagg(const int* __restrict__ row_start, const int* __restrict__ rcol_s,
                           const float* __restrict__ rw_s, const float* __restrict__ d_r,
                           const float* __restrict__ d_c, const float* __restrict__ tabS,
                           const float* __restrict__ cbf, const int* __restrict__ wmaxi,
                           int l, const float* __restrict__ pA, float* __restrict__ pB){
  int lane = threadIdx.x & 63;
  int n = (blockIdx.x*256 + threadIdx.x) >> 6;    // grid exact: NN/4
  const float* __restrict__ ts = tabS + l*TROWS;
  float invD = (float)(TROWS-1) / __int_as_float(*wmaxi);
  float cb = cbf[l] + d_r[n];
  int p0 = row_start[n], p1 = row_start[n+1];
  float px = pA[n*3+0], py = pA[n*3+1], pz = pA[n*3+2];
  float sx=0.f, sy=0.f, sz=0.f;
  for(int p = p0 + lane; p < p1; p += 64){
    int c = rcol_s[p];
    float w = rw_s[p];
    float tf = w*invD;
    int i0 = min((int)tf, TROWS-2);
    float fr = tf - (float)i0;
    float s0 = ts[i0], s1 = ts[i0+1];
    float acc = cb + d_c[c] + s0 + (s1-s0)*fr;
    sx += (px - pA[c*3+0])*acc;
    sy += (py - pA[c*3+1])*acc;
    sz += (pz - pA[c*3+2])*acc;
  }
  #pragma unroll
  for(int s=32; s>0; s>>=1){
    sx += __shfl_down(sx, s, 64);
    sy += __shfl_down(sy, s, 64);
    sz += __shfl_down(sz, s, 64);
  }
  if(lane == 0){
    int cnt = p1 - p0;
    float inv = (cnt > 0) ? 1.f/(float)cnt : 0.f;
    pB[n*3+0] = px + sx*inv;
    pB[n*3+1] = py + sy*inv;
    pB[n*3+2] = pz + sz*inv;
  }
}

// ---------- xf = h @ lin1^T (bf16 out) ----------
__global__ void k_xf(const float* __restrict__ h, const float* __restrict__ l1t,
                     int l, u16* __restrict__ xfb){
  int f = threadIdx.x;
  int n0 = blockIdx.x*8;                          // grid exact: NN/8
  const float* __restrict__ wt = l1t + l*HH*NF;
  float acc[8];
  #pragma unroll
  for(int i=0;i<8;i++) acc[i] = 0.f;
  for(int k=0;k<HH;k++){
    float wv = wt[k*NF + f];
    #pragma unroll
    for(int i=0;i<8;i++) acc[i] += h[(n0+i)*HH + k] * wv;
  }
  #pragma unroll
  for(int i=0;i<8;i++) xfb[(n0+i)*NF + f] = f2us(acc[i]);
}

// ---------- fused CFConv aggregation: agg[n][f] = sum_p xf[row][f]*lerp(tabG,w_p)[f] ----------
__global__ void k_cfagg(const int* __restrict__ col_start, const int* __restrict__ row_s,
                        const float* __restrict__ wEs, const u32* __restrict__ xfb32,
                        const float* __restrict__ tabG, const int* __restrict__ wmaxi,
                        int l, float* __restrict__ agg){
  int n = blockIdx.x*4 + (threadIdx.x >> 6);      // grid exact: NN/4
  int q = threadIdx.x & 63;                       // feature pair
  float invD = (float)(TROWS-1) / __int_as_float(*wmaxi);
  const float* __restrict__ tg = tabG + (size_t)l*TROWS*NF;
  int p0 = col_start[n], p1 = col_start[n+1];
  float a0=0.f, b0=0.f, a1=0.f, b1=0.f;
  int p = p0;
  for(; p+2 <= p1; p += 2){
    int r0 = row_s[p], r1 = row_s[p+1];
    float t0 = wEs[p]*invD, t1 = wEs[p+1]*invD;
    int i0 = min((int)t0, TROWS-2), i1 = min((int)t1, TROWS-2);
    float fr0 = t0 - (float)i0, fr1 = t1 - (float)i1;
    float2 ga0 = *(const float2*)&tg[i0*NF + 2*q];
    float2 gb0 = *(const float2*)&tg[(i0+1)*NF + 2*q];
    float2 ga1 = *(const float2*)&tg[i1*NF + 2*q];
    float2 gb1 = *(const float2*)&tg[(i1+1)*NF + 2*q];
    u32 x0 = xfb32[r0*64 + q], x1 = xfb32[r1*64 + q];
    a0 += us2f((u16)x0)        *(ga0.x + (gb0.x-ga0.x)*fr0);
    b0 += us2f((u16)(x0>>16))  *(ga0.y + (gb0.y-ga0.y)*fr0);
    a1 += us2f((u16)x1)        *(ga1.x + (gb1.x-ga1.x)*fr1);
    b1 += us2f((u16)(x1>>16))  *(ga1.y + (gb1.y-ga1.y)*fr1);
  }
  if(p < p1){
    int r0 = row_s[p];
    float t0 = wEs[p]*invD;
    int i0 = min((int)t0, TROWS-2);
    float fr0 = t0 - (float)i0;
    float2 ga0 = *(const float2*)&tg[i0*NF + 2*q];
    float2 gb0 = *(const float2*)&tg[(i0+1)*NF + 2*q];
    u32 x0 = xfb32[r0*64 + q];
    a0 += us2f((u16)x0)      *(ga0.x + (gb0.x-ga0.x)*fr0);
    b0 += us2f((u16)(x0>>16))*(ga0.y + (gb0.y-ga0.y)*fr0);
  }
  float2 r; r.x = a0+a1; r.y = b0+b1;
  *(float2*)&agg[n*NF + 2*q] = r;
}

// ---------- h += ssp(agg@lin2^T + b) @ lin^T + b ----------
__global__ void k_update(const float* __restrict__ agg, const float* __restrict__ l2t,
                         const float* __restrict__ l2bf, const float* __restrict__ lwt,
                         const float* __restrict__ lbf, int l, float* __restrict__ h){
  __shared__ float sg[HH*12];
  int f = threadIdx.x;
  int n0 = blockIdx.x*8;                          // grid exact: NN/8
  const float* __restrict__ wA = l2t + l*NF*HH;
  float bA = l2bf[l*HH + f];
  float acc[8];
  #pragma unroll
  for(int i=0;i<8;i++) acc[i] = bA;
  for(int k=0;k<NF;k++){
    float wv = wA[k*HH + f];
    #pragma unroll
    for(int i=0;i<8;i++) acc[i] += agg[(n0+i)*NF + k] * wv;
  }
  #pragma unroll
  for(int i=0;i<8;i++) sg[f*12 + i] = sspf(acc[i]);
  __syncthreads();
  const float* __restrict__ wB = lwt + l*HH*HH;
  float bB = lbf[l*HH + f];
  float acc2[8];
  #pragma unroll
  for(int i=0;i<8;i++) acc2[i] = bB;
  for(int k=0;k<HH;k++){
    float wv = wB[k*HH + f];
    #pragma unroll
    for(int i=0;i<8;i++) acc2[i] += sg[k*12 + i] * wv;
  }
  #pragma unroll
  for(int i=0;i<8;i++) h[(n0+i)*HH + f] += acc2[i];
}

__global__ void k_out(const float* __restrict__ pos, const float* __restrict__ h,
                      const int* __restrict__ flags, void* __restrict__ out){
  int i = blockIdx.x*256 + threadIdx.x;           // grid exact: NN*HH
  if(flags[0]){
    u16* o = (u16*)out;
    if(i < NN*3) o[i] = f2us(pos[i]);
    o[NN*3 + i] = f2us(h[i]);
  } else {
    float* o = (float*)out;
    if(i < NN*3) o[i] = pos[i];
    o[NN*3 + i] = h[i];
  }
}

extern "C" void kernel_launch(void* const* d_in, const int* in_sizes, int n_in,
                              void* d_out, int out_size, void* d_ws, size_t ws_size,
                              hipStream_t stream){
  const void* z      = d_in[0];
  const void* pos_in = d_in[1];
  const int*  ei_raw = (const int*)d_in[2];
  const void* mlp1_w = d_in[3];
  const void* mlp1_b = d_in[4];
  const void* mlp2_w = d_in[5];
  const void* mlp2_b = d_in[6];
  const void* lin1_w = d_in[7];
  const void* lin2_w = d_in[8];
  const void* lin2_b = d_in[9];
  const void* lin_w  = d_in[10];
  const void* lin_b  = d_in[11];
  const void* coord_w= d_in[12];
  const void* coord_b= d_in[13];

  float* W = (float*)d_ws;
  float* h    = W; W += NN*HH;
  float* agg  = W; W += NN*NF;
  float* posA = W; W += NN*3;
  float* posB = W; W += NN*3;
  float* d_r  = W; W += NN;
  float* d_c  = W; W += NN;
  float* wE   = W; W += EE;
  float* wEs  = W; W += EE;
  float* rw_s = W; W += EE;
  float* b1f  = W; W += NL*NF;
  float* b2v  = W; W += NL*NF;
  float* w1t  = W; W += NL*GG*NF;
  float* w2t  = W; W += NL*NF*NF;
  float* l1t  = W; W += NL*NF*HH;
  float* l2t  = W; W += NL*HH*NF;
  float* l2bf = W; W += NL*HH;
  float* lwt  = W; W += NL*HH*HH;
  float* lbf  = W; W += NL*HH;
  float* cwf  = W; W += NL*(GG+2*HH);
  float* cbf  = W; W += NL;
  W = (float*)(((uintptr_t)W + 63) & ~(uintptr_t)63);
  float* tabG = W; W += (size_t)NL*TROWS*NF;      // 6 MB fp32
  float* tabS = W; W += NL*TROWS;
  u16* xfb = (u16*)W; W += (NN*NF)/2;             // bf16 xf
  int* deg_row   = (int*)W; W += NN;
  int* col_deg   = (int*)W; W += NN;
  int* col_start = (int*)W; W += NN+1;
  int* col_next  = (int*)W; W += NN;
  int* row_start = (int*)W; W += NN+1;
  int* row_next  = (int*)W; W += NN;
  int* row_s     = (int*)W; W += EE;
  int* rcol_s    = (int*)W; W += EE;
  int* eiN       = (int*)W; W += 2*EE;
  int* flags     = (int*)W; W += 2;
  int* wmaxi     = (int*)W; W += 1;

  hipMemsetAsync(deg_row, 0, NN*sizeof(int), stream);
  hipMemsetAsync(col_deg, 0, NN*sizeof(int), stream);
  hipMemsetAsync(wmaxi, 0, sizeof(int), stream);

  k_dtype<<<1, 256, 0, stream>>>((const u32*)z, ei_raw, flags);
  k_norm<<<(2*EE)/256, 256, 0, stream>>>(ei_raw, flags, eiN);
  k_prep_weights<<<(NL*NF*NF)/256, 256, 0, stream>>>(
      mlp1_w, mlp1_b, mlp2_w, mlp2_b, lin1_w, lin2_w, lin2_b, lin_w, lin_b,
      coord_w, coord_b, flags,
      b1f, b2v, w1t, w2t, l1t, l2t, l2bf, lwt, lbf, cwf, cbf);
  k_init<<<(NN*HH)/256, 256, 0, stream>>>(z, pos_in, flags, h, posA);
  k_edge_prep<<<EE/256, 256, 0, stream>>>(eiN, posA, wE, deg_row, col_deg, wmaxi);
  k_scan<<<1, 1024, 0, stream>>>(col_deg, col_start, col_next);
  k_scan<<<1, 1024, 0, stream>>>(deg_row, row_start, row_next);
  k_fillC<<<EE/256, 256, 0, stream>>>(eiN, wE, col_next, row_s, wEs);
  k_fillR<<<EE/256, 256, 0, stream>>>(eiN, wE, row_next, rcol_s, rw_s);
  k_table<<<dim3(TROWS/8, NL), 128, 0, stream>>>(w1t, b1f, w2t, b2v, cwf, wmaxi,
                                                 tabG, tabS);

  float* pA = posA;
  float* pB = posB;
  for(int l=0; l<NL; l++){
    k_nodedot<<<NN/4, 256, 0, stream>>>(h, cwf, l, d_r, d_c);
    k_coordagg<<<NN/4, 256, 0, stream>>>(row_start, rcol_s, rw_s, d_r, d_c,
                                         tabS, cbf, wmaxi, l, pA, pB);
    k_xf<<<NN/8, 128, 0, stream>>>(h, l1t, l, xfb);
    k_cfagg<<<NN/4, 256, 0, stream>>>(col_start, row_s, wEs, (const u32*)xfb,
                                      tabG, wmaxi, l, agg);
    k_update<<<NN/8, 128, 0, stream>>>(agg, l2t, l2bf, lwt, lbf, l, h);
    float* tmp = pA; pA = pB; pB = tmp;
  }
  // NL even -> final pos back in posA
  k_out<<<(NN*HH)/256, 256, 0, stream>>>(pA, h, flags, (void*)d_out);
}

// Round 7
// 803.462 us; speedup vs baseline: 1.9036x; 1.0639x over previous
//
#include <hip/hip_runtime.h>

// SchNet on MI355X — round 7: wave-reduced wmax atomic, fused launches
// (fill, scans, nodedot+xf, coordagg+cfagg), paired-bf16 lookup table
// (one u32 load = both lerp endpoints). Table-based edge MLP retained.

#define NN 10000
#define EE 320000
#define HH 128
#define GG 50
#define NF 128
#define NL 6
#define TROWS 2048

typedef unsigned short u16;
typedef unsigned int u32;

__device__ __forceinline__ float us2f(u16 u){
  union { float f; u32 i; } v; v.i = ((u32)u) << 16; return v.f;
}
__device__ __forceinline__ u16 f2us(float x){
  union { float f; u32 i; } v; v.f = x;
  u32 r = v.i + 0x7fffu + ((v.i >> 16) & 1u);   // RNE
  return (u16)(r >> 16);
}
__device__ __forceinline__ float ldin(const void* p, int i, int bf){
  return bf ? us2f(((const u16*)p)[i]) : ((const float*)p)[i];
}
__device__ __forceinline__ float sspf(float x){
  return fmaxf(x, 0.f) + __logf(1.f + __expf(-fabsf(x))) - 0.6931472f;
}

// ---------- dtype detection ----------
__global__ void k_dtype(const u32* __restrict__ zraw, const int* __restrict__ ei_raw,
                        int* __restrict__ flags){
  __shared__ int votes[2];
  if(threadIdx.x < 2) votes[threadIdx.x] = 0;
  __syncthreads();
  int v0 = 0, v1 = 0;
  for(int i = threadIdx.x; i < 4096; i += 256){
    u32 w = zraw[i];
    u32 hb = (w >> 8) & 0x7F;
    if(hb >= 0x38 && hb <= 0x41) v0++;
    if(ei_raw[2*i + 1] == 0) v1++;
  }
  atomicAdd(&votes[0], v0); atomicAdd(&votes[1], v1);
  __syncthreads();
  if(threadIdx.x == 0){
    flags[0] = (votes[0] > 2048) ? 1 : 0;
    flags[1] = (votes[1] > 4000) ? 1 : 0;
  }
}

__global__ void k_norm(const int* __restrict__ ei_raw, const int* __restrict__ flags,
                       int* __restrict__ eiN){
  int j = blockIdx.x*256 + threadIdx.x;           // grid exact: 2*EE
  eiN[j] = flags[1] ? ei_raw[2*j] : ei_raw[j];
}

// ---------- weight staging ----------
__global__ void k_prep_weights(
    const void* __restrict__ mlp1_w, const void* __restrict__ mlp1_b,
    const void* __restrict__ mlp2_w, const void* __restrict__ mlp2_b,
    const void* __restrict__ lin1_w, const void* __restrict__ lin2_w,
    const void* __restrict__ lin2_b, const void* __restrict__ lin_w,
    const void* __restrict__ lin_b,  const void* __restrict__ coord_w,
    const void* __restrict__ coord_b, const int* __restrict__ flags,
    float* __restrict__ b1f, float* __restrict__ b2v,
    float* __restrict__ w1t, float* __restrict__ w2t,
    float* __restrict__ l1t, float* __restrict__ l2t,
    float* __restrict__ l2bf, float* __restrict__ lwt,
    float* __restrict__ lbf, float* __restrict__ cwf, float* __restrict__ cbf)
{
  int i = blockIdx.x*256 + threadIdx.x;           // grid exact: NL*NF*NF
  int bf = flags[0];
  if(i < NL*NF){
    b1f[i]  = ldin(mlp1_b, i, bf);
    b2v[i]  = ldin(mlp2_b, i, bf);
    l2bf[i] = ldin(lin2_b, i, bf);
    lbf[i]  = ldin(lin_b,  i, bf);
  }
  if(i < NL*GG*NF){                               // w1t[l][g][f] = mlp1_w[l][f][g]
    int l = i/(GG*NF), rem = i%(GG*NF);
    int g = rem/NF, f = rem%NF;
    w1t[i] = ldin(mlp1_w, (l*NF + f)*GG + g, bf);
  }
  if(i < NL*NF*NF){
    int l = i/(NF*NF), rem = i%(NF*NF);
    int k = rem/NF, f = rem%NF;
    w2t[i] = ldin(mlp2_w, l*NF*NF + f*NF + k, bf);
    l1t[i] = ldin(lin1_w, l*NF*HH + f*HH + k, bf);
    l2t[i] = ldin(lin2_w, l*HH*NF + f*NF + k, bf);
    lwt[i] = ldin(lin_w,  l*HH*HH + f*HH + k, bf);
  }
  if(i < NL*(GG+2*HH)) cwf[i] = ldin(coord_w, i, bf);
  if(i < NL) cbf[i] = ldin(coord_b, i, bf);
}

__global__ void k_init(const void* __restrict__ z, const void* __restrict__ pos_in,
                       const int* __restrict__ flags,
                       float* __restrict__ h, float* __restrict__ pos){
  int i = blockIdx.x*256 + threadIdx.x;           // grid exact: NN*HH
  int bf = flags[0];
  h[i] = ldin(z, i, bf);
  if(i < NN*3) pos[i] = ldin(pos_in, i, bf);
}

// ---------- edge prep: distances, degrees, wave-reduced w_max ----------
__global__ void k_edge_prep(const int* __restrict__ eiN, const float* __restrict__ pos,
                            float* __restrict__ wE,
                            int* __restrict__ deg_row, int* __restrict__ col_deg,
                            int* __restrict__ wmaxi){
  int e = blockIdx.x*256 + threadIdx.x;           // grid exact: EE
  int r = eiN[e], c = eiN[EE+e];
  float dx = pos[r*3+0]-pos[c*3+0];
  float dy = pos[r*3+1]-pos[c*3+1];
  float dz = pos[r*3+2]-pos[c*3+2];
  float w = sqrtf(dx*dx + dy*dy + dz*dz);
  wE[e] = w;
  float wm = w;
  #pragma unroll
  for(int s=32; s>0; s>>=1) wm = fmaxf(wm, __shfl_down(wm, s, 64));
  if((threadIdx.x & 63) == 0) atomicMax(wmaxi, __float_as_int(wm));  // 1 per wave
  atomicAdd(&deg_row[r], 1);
  atomicAdd(&col_deg[c], 1);
}

// ---------- fused dual exclusive scan (col_deg and deg_row) ----------
__global__ void k_scan2(const int* __restrict__ col_deg, const int* __restrict__ deg_row,
                        int* __restrict__ col_start, int* __restrict__ col_next,
                        int* __restrict__ row_start, int* __restrict__ row_next){
  __shared__ int part[1024];
  int tid = threadIdx.x;
  const int CH = (NN + 1023)/1024;
  for(int pass=0; pass<2; pass++){
    const int* deg = pass ? deg_row : col_deg;
    int* start = pass ? row_start : col_start;
    int* nxt   = pass ? row_next  : col_next;
    int base = tid*CH;
    int s = 0;
    for(int i=0;i<CH;i++){ int idx=base+i; if(idx<NN) s += deg[idx]; }
    part[tid] = s;
    __syncthreads();
    for(int off=1; off<1024; off<<=1){
      int v = (tid>=off) ? part[tid-off] : 0;
      __syncthreads();
      part[tid] += v;
      __syncthreads();
    }
    int run = (tid==0) ? 0 : part[tid-1];
    for(int i=0;i<CH;i++){
      int idx = base+i;
      if(idx<NN){ start[idx]=run; nxt[idx]=run; run += deg[idx]; }
    }
    if(tid==1023) start[NN] = run;
    __syncthreads();
  }
}

// ---------- fused CSR fill (col-CSR for cfagg, row-CSR for coordagg) ----------
__global__ void k_fill(const int* __restrict__ eiN, const float* __restrict__ wE,
                       int* __restrict__ col_next, int* __restrict__ row_next,
                       int* __restrict__ row_s, float* __restrict__ wEs,
                       int* __restrict__ rcol_s, float* __restrict__ rw_s){
  int e = blockIdx.x*256 + threadIdx.x;           // grid exact: EE
  int r = eiN[e], c = eiN[EE+e];
  float w = wE[e];
  int p = atomicAdd(&col_next[c], 1);
  row_s[p] = r; wEs[p] = w;
  int p2 = atomicAdd(&row_next[r], 1);
  rcol_s[p2] = c; rw_s[p2] = w;
}

// ---------- build fp32 tables for all layers ----------
__global__ void k_table(const float* __restrict__ w1t, const float* __restrict__ b1f,
                        const float* __restrict__ w2t, const float* __restrict__ b2v,
                        const float* __restrict__ cwf, const int* __restrict__ wmaxi,
                        float* __restrict__ tabG, float* __restrict__ tabS){
  __shared__ float attr[8][64];
  __shared__ float tls[128][9];
  int f = threadIdx.x;                            // 128
  int l = blockIdx.y;
  int r0 = blockIdx.x*8;
  float delta = __int_as_float(*wmaxi) / (float)(TROWS-1);
  for(int idx=f; idx<8*64; idx+=128){
    int r = idx>>6, g = idx&63;
    float w = (float)(r0+r)*delta;
    float d = w - (float)g*(10.f/49.f);
    attr[r][g] = (g < GG) ? __expf(-12.005f*d*d) : 0.f;
  }
  __syncthreads();
  const float* __restrict__ w1 = w1t + l*GG*NF;
  float b1 = b1f[l*NF + f];
  float acc[8];
  #pragma unroll
  for(int r=0;r<8;r++) acc[r] = b1;
  for(int g=0; g<GG; g++){
    float wv = w1[g*NF + f];
    #pragma unroll
    for(int r=0;r<8;r++) acc[r] += attr[r][g]*wv;
  }
  #pragma unroll
  for(int r=0;r<8;r++) tls[f][r] = sspf(acc[r]);
  __syncthreads();
  const float* __restrict__ w2 = w2t + l*NF*NF;
  float b2 = b2v[l*NF + f];
  float acc2[8];
  #pragma unroll
  for(int r=0;r<8;r++) acc2[r] = b2;
  for(int k=0;k<NF;k++){
    float wv = w2[k*NF + f];
    #pragma unroll
    for(int r=0;r<8;r++) acc2[r] += tls[k][r]*wv;
  }
  #pragma unroll
  for(int r=0;r<8;r++){
    float w = (float)(r0+r)*delta;
    float C = 0.5f*(cosf(w*0.3141592653589793f) + 1.f);
    tabG[((size_t)l*TROWS + r0 + r)*NF + f] = acc2[r]*C;
  }
  if(f < 8){
    const float* __restrict__ cwg = cwf + l*(GG+2*HH);
    float s = 0.f;
    for(int g=0; g<GG; g++) s += attr[f][g]*cwg[g];
    tabS[l*TROWS + r0 + f] = s;
  }
}

// ---------- pack tabG into paired bf16: u32 = (G[i][f], G[i+1][f]) ----------
__global__ void k_pack(const float* __restrict__ tabG, u32* __restrict__ tabGb){
  int i = blockIdx.x*256 + threadIdx.x;           // grid exact: NL*TROWS*NF/256
  int row = (i / NF) % TROWS;
  float g0 = tabG[i];
  float g1 = (row < TROWS-1) ? tabG[i + NF] : g0;
  tabGb[i] = (u32)f2us(g0) | ((u32)f2us(g1) << 16);
}

// ---------- fused per-node kernel: xf (blocks 0..NN/8) + nodedot (rest) ----------
__global__ void k_node(const float* __restrict__ h, const float* __restrict__ l1t,
                       const float* __restrict__ cwf, int l,
                       u16* __restrict__ xfb, float* __restrict__ d_r,
                       float* __restrict__ d_c){
  int b = blockIdx.x;                             // grid: NN/8 + NN/4
  if(b < NN/8){
    int f = threadIdx.x & 127;
    int n0 = b*8 + (threadIdx.x >> 7)*4;          // 256 thr: 2 halves x 4 nodes
    const float* __restrict__ wt = l1t + l*HH*NF;
    float acc[4] = {0.f,0.f,0.f,0.f};
    for(int k=0;k<HH;k++){
      float wv = wt[k*NF + f];
      #pragma unroll
      for(int i=0;i<4;i++) acc[i] += h[(n0+i)*HH + k] * wv;  // uniform -> s_load
    }
    #pragma unroll
    for(int i=0;i<4;i++) xfb[(n0+i)*NF + f] = f2us(acc[i]);
  } else {
    int lane = threadIdx.x & 63;
    int n = (b - NN/8)*4 + (threadIdx.x >> 6);
    const float* __restrict__ cw = cwf + l*(GG + 2*HH);
    float h0 = h[n*HH + lane], h1 = h[n*HH + 64 + lane];
    float ar = h0*cw[GG + lane]      + h1*cw[GG + 64 + lane];
    float ac = h0*cw[GG + HH + lane] + h1*cw[GG + HH + 64 + lane];
    #pragma unroll
    for(int s=32; s>0; s>>=1){
      ar += __shfl_down(ar, s, 64);
      ac += __shfl_down(ac, s, 64);
    }
    if(lane == 0){ d_r[n] = ar; d_c[n] = ac; }
  }
}

// ---------- fused aggregation: cfagg (blocks 0..NN/4) + coordagg (rest) ----------
__global__ void k_agg(const int* __restrict__ col_start, const int* __restrict__ row_s,
                      const float* __restrict__ wEs, const u32* __restrict__ xfb32,
                      const u32* __restrict__ tabGb, const int* __restrict__ wmaxi,
                      int l, float* __restrict__ agg,
                      const int* __restrict__ row_start, const int* __restrict__ rcol_s,
                      const float* __restrict__ rw_s, const float* __restrict__ d_r,
                      const float* __restrict__ d_c, const float* __restrict__ tabS,
                      const float* __restrict__ cbf,
                      const float* __restrict__ pA, float* __restrict__ pB){
  int b = blockIdx.x;                             // grid: NN/4 + NN/4
  float invD = (float)(TROWS-1) / __int_as_float(*wmaxi);
  if(b < NN/4){
    // CFConv aggregation with paired-bf16 table lerp
    int n = b*4 + (threadIdx.x >> 6);
    int q = threadIdx.x & 63;                     // feature pair
    const u32* __restrict__ tg = tabGb + (size_t)l*TROWS*NF;
    int p0 = col_start[n], p1 = col_start[n+1];
    float a0=0.f, b0=0.f, a1=0.f, b1=0.f;
    int p = p0;
    for(; p+2 <= p1; p += 2){
      int r0 = row_s[p], r1 = row_s[p+1];
      float t0 = wEs[p]*invD, t1 = wEs[p+1]*invD;
      int i0 = min((int)t0, TROWS-2), i1 = min((int)t1, TROWS-2);
      float fr0 = t0 - (float)i0, fr1 = t1 - (float)i1;
      uint2 pr0 = *(const uint2*)&tg[i0*NF + 2*q];
      uint2 pr1 = *(const uint2*)&tg[i1*NF + 2*q];
      u32 x0 = xfb32[r0*64 + q], x1 = xfb32[r1*64 + q];
      float lo, hi;
      lo = us2f((u16)pr0.x); hi = us2f((u16)(pr0.x>>16));
      a0 += us2f((u16)x0)      *(lo + (hi-lo)*fr0);
      lo = us2f((u16)pr0.y); hi = us2f((u16)(pr0.y>>16));
      b0 += us2f((u16)(x0>>16))*(lo + (hi-lo)*fr0);
      lo = us2f((u16)pr1.x); hi = us2f((u16)(pr1.x>>16));
      a1 += us2f((u16)x1)      *(lo + (hi-lo)*fr1);
      lo = us2f((u16)pr1.y); hi = us2f((u16)(pr1.y>>16));
      b1 += us2f((u16)(x1>>16))*(lo + (hi-lo)*fr1);
    }
    if(p < p1){
      int r0 = row_s[p];
      float t0 = wEs[p]*invD;
      int i0 = min((int)t0, TROWS-2);
      float fr0 = t0 - (float)i0;
      uint2 pr0 = *(const uint2*)&tg[i0*NF + 2*q];
      u32 x0 = xfb32[r0*64 + q];
      float lo, hi;
      lo = us2f((u16)pr0.x); hi = us2f((u16)(pr0.x>>16));
      a0 += us2f((u16)x0)      *(lo + (hi-lo)*fr0);
      lo = us2f((u16)pr0.y); hi = us2f((u16)(pr0.y>>16));
      b0 += us2f((u16)(x0>>16))*(lo + (hi-lo)*fr0);
    }
    float2 r; r.x = a0+a1; r.y = b0+b1;
    *(float2*)&agg[n*NF + 2*q] = r;
  } else {
    // coordinate update
    int lane = threadIdx.x & 63;
    int n = (b - NN/4)*4 + (threadIdx.x >> 6);
    const float* __restrict__ ts = tabS + l*TROWS;
    float cb = cbf[l] + d_r[n];
    int p0 = row_start[n], p1 = row_start[n+1];
    float px = pA[n*3+0], py = pA[n*3+1], pz = pA[n*3+2];
    float sx=0.f, sy=0.f, sz=0.f;
    for(int p = p0 + lane; p < p1; p += 64){
      int c = rcol_s[p];
      float tf = rw_s[p]*invD;
      int i0 = min((int)tf, TROWS-2);
      float fr = tf - (float)i0;
      float s0 = ts[i0], s1 = ts[i0+1];
      float acc = cb + d_c[c] + s0 + (s1-s0)*fr;
      sx += (px - pA[c*3+0])*acc;
      sy += (py - pA[c*3+1])*acc;
      sz += (pz - pA[c*3+2])*acc;
    }
    #pragma unroll
    for(int s=32; s>0; s>>=1){
      sx += __shfl_down(sx, s, 64);
      sy += __shfl_down(sy, s, 64);
      sz += __shfl_down(sz, s, 64);
    }
    if(lane == 0){
      int cnt = p1 - p0;
      float inv = (cnt > 0) ? 1.f/(float)cnt : 0.f;
      pB[n*3+0] = px + sx*inv;
      pB[n*3+1] = py + sy*inv;
      pB[n*3+2] = pz + sz*inv;
    }
  }
}

// ---------- h += ssp(agg@lin2^T + b) @ lin^T + b ----------
__global__ void k_update(const float* __restrict__ agg, const float* __restrict__ l2t,
                         const float* __restrict__ l2bf, const float* __restrict__ lwt,
                         const float* __restrict__ lbf, int l, float* __restrict__ h){
  __shared__ float sg[HH*12];
  int f = threadIdx.x;
  int n0 = blockIdx.x*8;                          // grid exact: NN/8
  const float* __restrict__ wA = l2t + l*NF*HH;
  float bA = l2bf[l*HH + f];
  float acc[8];
  #pragma unroll
  for(int i=0;i<8;i++) acc[i] = bA;
  for(int k=0;k<NF;k++){
    float wv = wA[k*HH + f];
    #pragma unroll
    for(int i=0;i<8;i++) acc[i] += agg[(n0+i)*NF + k] * wv;
  }
  #pragma unroll
  for(int i=0;i<8;i++) sg[f*12 + i] = sspf(acc[i]);
  __syncthreads();
  const float* __restrict__ wB = lwt + l*HH*HH;
  float bB = lbf[l*HH + f];
  float acc2[8];
  #pragma unroll
  for(int i=0;i<8;i++) acc2[i] = bB;
  for(int k=0;k<HH;k++){
    float wv = wB[k*HH + f];
    #pragma unroll
    for(int i=0;i<8;i++) acc2[i] += sg[k*12 + i] * wv;
  }
  #pragma unroll
  for(int i=0;i<8;i++) h[(n0+i)*HH + f] += acc2[i];
}

__global__ void k_out(const float* __restrict__ pos, const float* __restrict__ h,
                      const int* __restrict__ flags, void* __restrict__ out){
  int i = blockIdx.x*256 + threadIdx.x;           // grid exact: NN*HH
  if(flags[0]){
    u16* o = (u16*)out;
    if(i < NN*3) o[i] = f2us(pos[i]);
    o[NN*3 + i] = f2us(h[i]);
  } else {
    float* o = (float*)out;
    if(i < NN*3) o[i] = pos[i];
    o[NN*3 + i] = h[i];
  }
}

extern "C" void kernel_launch(void* const* d_in, const int* in_sizes, int n_in,
                              void* d_out, int out_size, void* d_ws, size_t ws_size,
                              hipStream_t stream){
  const void* z      = d_in[0];
  const void* pos_in = d_in[1];
  const int*  ei_raw = (const int*)d_in[2];
  const void* mlp1_w = d_in[3];
  const void* mlp1_b = d_in[4];
  const void* mlp2_w = d_in[5];
  const void* mlp2_b = d_in[6];
  const void* lin1_w = d_in[7];
  const void* lin2_w = d_in[8];
  const void* lin2_b = d_in[9];
  const void* lin_w  = d_in[10];
  const void* lin_b  = d_in[11];
  const void* coord_w= d_in[12];
  const void* coord_b= d_in[13];

  float* W = (float*)d_ws;
  float* h    = W; W += NN*HH;
  float* agg  = W; W += NN*NF;
  float* posA = W; W += NN*3;
  float* posB = W; W += NN*3;
  float* d_r  = W; W += NN;
  float* d_c  = W; W += NN;
  float* wE   = W; W += EE;
  float* wEs  = W; W += EE;
  float* rw_s = W; W += EE;
  float* b1f  = W; W += NL*NF;
  float* b2v  = W; W += NL*NF;
  float* w1t  = W; W += NL*GG*NF;
  float* w2t  = W; W += NL*NF*NF;
  float* l1t  = W; W += NL*NF*HH;
  float* l2t  = W; W += NL*HH*NF;
  float* l2bf = W; W += NL*HH;
  float* lwt  = W; W += NL*HH*HH;
  float* lbf  = W; W += NL*HH;
  float* cwf  = W; W += NL*(GG+2*HH);
  float* cbf  = W; W += NL;
  W = (float*)(((uintptr_t)W + 63) & ~(uintptr_t)63);
  float* tabG = W; W += (size_t)NL*TROWS*NF;      // fp32 table (build)
  float* tabS = W; W += NL*TROWS;
  u32*  tabGb = (u32*)W; W += (size_t)NL*TROWS*NF; // paired bf16 table (consume)
  u16* xfb = (u16*)W; W += (NN*NF)/2;
  int* deg_row   = (int*)W; W += NN;
  int* col_deg   = (int*)W; W += NN;
  int* col_start = (int*)W; W += NN+1;
  int* col_next  = (int*)W; W += NN;
  int* row_start = (int*)W; W += NN+1;
  int* row_next  = (int*)W; W += NN;
  int* row_s     = (int*)W; W += EE;
  int* rcol_s    = (int*)W; W += EE;
  int* eiN       = (int*)W; W += 2*EE;
  int* flags     = (int*)W; W += 2;
  int* wmaxi     = (int*)W; W += 1;

  hipMemsetAsync(deg_row, 0, NN*sizeof(int), stream);
  hipMemsetAsync(col_deg, 0, NN*sizeof(int), stream);
  hipMemsetAsync(wmaxi, 0, sizeof(int), stream);

  k_dtype<<<1, 256, 0, stream>>>((const u32*)z, ei_raw, flags);
  k_norm<<<(2*EE)/256, 256, 0, stream>>>(ei_raw, flags, eiN);
  k_prep_weights<<<(NL*NF*NF)/256, 256, 0, stream>>>(
      mlp1_w, mlp1_b, mlp2_w, mlp2_b, lin1_w, lin2_w, lin2_b, lin_w, lin_b,
      coord_w, coord_b, flags,
      b1f, b2v, w1t, w2t, l1t, l2t, l2bf, lwt, lbf, cwf, cbf);
  k_init<<<(NN*HH)/256, 256, 0, stream>>>(z, pos_in, flags, h, posA);
  k_edge_prep<<<EE/256, 256, 0, stream>>>(eiN, posA, wE, deg_row, col_deg, wmaxi);
  k_scan2<<<1, 1024, 0, stream>>>(col_deg, deg_row, col_start, col_next,
                                  row_start, row_next);
  k_fill<<<EE/256, 256, 0, stream>>>(eiN, wE, col_next, row_next,
                                     row_s, wEs, rcol_s, rw_s);
  k_table<<<dim3(TROWS/8, NL), 128, 0, stream>>>(w1t, b1f, w2t, b2v, cwf, wmaxi,
                                                 tabG, tabS);
  k_pack<<<(NL*TROWS*NF)/256, 256, 0, stream>>>(tabG, tabGb);

  float* pA = posA;
  float* pB = posB;
  for(int l=0; l<NL; l++){
    k_node<<<NN/8 + NN/4, 256, 0, stream>>>(h, l1t, cwf, l, xfb, d_r, d_c);
    k_agg<<<NN/4 + NN/4, 256, 0, stream>>>(col_start, row_s, wEs, (const u32*)xfb,
                                           tabGb, wmaxi, l, agg,
                                           row_start, rcol_s, rw_s, d_r, d_c,
                                           tabS, cbf, pA, pB);
    k_update<<<NN/8, 128, 0, stream>>>(agg, l2t, l2bf, lwt, lbf, l, h);
    float* tmp = pA; pA = pB; pB = tmp;
  }
  // NL even -> final pos back in posA
  k_out<<<(NN*HH)/256, 256, 0, stream>>>(pA, h, flags, (void*)d_out);
}